// Round 12
// baseline (430.524 us; speedup 1.0000x reference)
//
#include <hip/hip_runtime.h>
#include <cstdint>
#include <cstddef>

#define HD 128  // hidden channels

typedef __attribute__((ext_vector_type(8))) short bf16x8;
typedef __attribute__((ext_vector_type(4))) float f32x4;

static inline int ceil_div(int a, int b) { return (a + b - 1) / b; }
static inline int imax(int a, int b) { return a > b ? a : b; }

// f32 -> bf16 (RNE) as raw bits
__device__ __forceinline__ unsigned short f2bf(float f) {
  unsigned u = __float_as_uint(f);
  return (unsigned short)((u + 0x7FFFu + ((u >> 16) & 1u)) >> 16);
}

// ============ bucket sort of edges (64 dst-nodes per bucket) ============
__global__ __launch_bounds__(256) void k_bhist(const int* __restrict__ ei, int nE,
                                               int* __restrict__ histT, int nbT,
                                               int* __restrict__ histS, int nbS) {
  __shared__ int h[1600];
  int nb = nbT + nbS;
  for (int i = threadIdx.x; i < nb; i += 256) h[i] = 0;
  __syncthreads();
  int stride = gridDim.x * 256;
  for (int e = blockIdx.x * 256 + threadIdx.x; e < nE; e += stride) {
    int s = ei[e];
    int t = ei[nE + e];
    atomicAdd(&h[t >> 6], 1);
    atomicAdd(&h[nbT + (s >> 6)], 1);
  }
  __syncthreads();
  for (int i = threadIdx.x; i < nb; i += 256) {
    int v = h[i];
    if (v) {
      if (i < nbT) atomicAdd(&histT[i], v);
      else atomicAdd(&histS[i - nbT], v);
    }
  }
}

__global__ __launch_bounds__(1024) void k_bscan(int* __restrict__ histA, int* __restrict__ offA, int nA,
                                                int* __restrict__ histB, int* __restrict__ offB, int nB) {
  int* hist = blockIdx.x ? histB : histA;
  int* off = blockIdx.x ? offB : offA;
  int n = blockIdx.x ? nB : nA;
  __shared__ int wsum[16];
  int tid = threadIdx.x;
  int lane = tid & 63;
  int wid = tid >> 6;
  int v = (tid < n) ? hist[tid] : 0;
  int x = v;
#pragma unroll
  for (int d = 1; d < 64; d <<= 1) {
    int y = __shfl_up(x, d, 64);
    if (lane >= d) x += y;
  }
  if (lane == 63) wsum[wid] = x;
  __syncthreads();
  if (wid == 0) {
    int s = (lane < 16) ? wsum[lane] : 0;
#pragma unroll
    for (int d = 1; d < 16; d <<= 1) {
      int y = __shfl_up(s, d, 64);
      if (lane >= d) s += y;
    }
    if (lane < 16) wsum[lane] = s;
  }
  __syncthreads();
  int wofs = (wid > 0) ? wsum[wid - 1] : 0;
  int exc = wofs + x - v;
  if (tid < n) {
    off[tid] = exc;
    hist[tid] = exc;  // cursor
  }
  if (tid == 0) off[n] = wsum[15];
}

#define SC_CH 4096  // edges per scatter block (256 thr x 16)
__global__ __launch_bounds__(256) void k_bscatter(const int* __restrict__ ei, int nE,
                                                  int* __restrict__ curT, int nbT,
                                                  unsigned* __restrict__ ebufT,
                                                  int* __restrict__ curS, int nbS,
                                                  unsigned* __restrict__ ebufS) {
  __shared__ unsigned epk[SC_CH];
  __shared__ int cntT[800], baseT[800], cntS[800], baseS[800];
  int tid = threadIdx.x;
  int e0 = blockIdx.x * SC_CH;
  for (int i = tid; i < nbT; i += 256) cntT[i] = 0;
  for (int i = tid; i < nbS; i += 256) cntS[i] = 0;
  for (int i = tid; i < SC_CH; i += 256) {
    int e = e0 + i;
    epk[i] = (e < nE) ? (((unsigned)ei[e] << 16) | (unsigned)ei[nE + e]) : 0xFFFFFFFFu;
  }
  __syncthreads();
  int rT[16], rS[16];
#pragma unroll
  for (int j = 0; j < 16; ++j) {
    int i = tid * 16 + j;
    unsigned p = epk[i];
    if (p != 0xFFFFFFFFu) {
      int t = (int)(p & 0xFFFFu);
      int s = (int)(p >> 16);
      rT[j] = atomicAdd(&cntT[t >> 6], 1);
      rS[j] = atomicAdd(&cntS[s >> 6], 1);
    }
  }
  __syncthreads();
  for (int b = tid; b < nbT; b += 256) baseT[b] = cntT[b] ? atomicAdd(&curT[b], cntT[b]) : 0;
  for (int b = tid; b < nbS; b += 256) baseS[b] = cntS[b] ? atomicAdd(&curS[b], cntS[b]) : 0;
  __syncthreads();
#pragma unroll
  for (int j = 0; j < 16; ++j) {
    int i = tid * 16 + j;
    unsigned p = epk[i];
    if (p != 0xFFFFFFFFu) {
      unsigned t = p & 0xFFFFu;
      unsigned s = p >> 16;
      ebufT[baseT[t >> 6] + rT[j]] = (s << 6) | (t & 63u);
      ebufS[baseS[s >> 6] + rS[j]] = (t << 6) | (s & 63u);
    }
  }
}

// ============ per-bucket counting sort -> per-node CSR padded to x4 ============
// Pad entries = zoff (zero row). Padded region of bucket b starts at
// boff[b] + 192*b (<=192 pad slots per bucket: 64 nodes x up to 3).
__global__ __launch_bounds__(256) void k_bsort2(
    const unsigned* __restrict__ ebufT, const int* __restrict__ boffT,
    int* __restrict__ poffT, int* __restrict__ degT, int* __restrict__ adjT,
    int nT, int nbT,
    const unsigned* __restrict__ ebufS, const int* __restrict__ boffS,
    int* __restrict__ poffS, int* __restrict__ degS, int* __restrict__ adjS,
    int nS, int zoff) {
  __shared__ int cnt[64];
  __shared__ int pos[64];
  int b = blockIdx.x;
  const unsigned* ebuf;
  const int* boff;
  int* poff;
  int* deg;
  int* adj;
  int ndst, bb;
  if (b < nbT) {
    ebuf = ebufT; boff = boffT; poff = poffT; deg = degT; adj = adjT;
    ndst = nT; bb = b;
  } else {
    ebuf = ebufS; boff = boffS; poff = poffS; deg = degS; adj = adjS;
    ndst = nS; bb = b - nbT;
  }
  int tid = threadIdx.x;
  if (tid < 64) cnt[tid] = 0;
  __syncthreads();
  int beg = boff[bb], end = boff[bb + 1];
  for (int k = beg + tid; k < end; k += 256) {
    atomicAdd(&cnt[ebuf[k] & 63u], 1);
  }
  __syncthreads();
  int vDeg = 0, pvPad = 0, startPos = 0;
  if (tid < 64) {
    vDeg = cnt[tid];
    pvPad = (vDeg + 3) & ~3;
    int x = pvPad;
#pragma unroll
    for (int d = 1; d < 64; d <<= 1) {
      int y = __shfl_up(x, d, 64);
      if (tid >= d) x += y;
    }
    startPos = beg + bb * 192 + x - pvPad;
    pos[tid] = startPos;
    int node = (bb << 6) + tid;
    if (node < ndst) {
      poff[node] = startPos;
      deg[node] = vDeg;
    }
  }
  __syncthreads();
  for (int k = beg + tid; k < end; k += 256) {
    unsigned e = ebuf[k];
    int p = atomicAdd(&pos[e & 63u], 1);
    adj[p] = (int)((e >> 6) << 8);  // byte offset = src * 256
  }
  __syncthreads();
  if (tid < 64) {
    for (int p = startPos + vDeg; p < startPos + pvPad; ++p) adj[p] = zoff;
  }
}

// ============ gather-cast + pad-row zeroing (4 tables) ============
__global__ __launch_bounds__(256) void k_cast_gather(
    const float* __restrict__ embA, const int* __restrict__ mapA,
    unsigned short* __restrict__ outA, int nA,
    const float* __restrict__ embB, const int* __restrict__ mapB,
    unsigned short* __restrict__ outB, int nB, int padRow,
    unsigned short* __restrict__ padC, unsigned short* __restrict__ padD) {
  int tid = blockIdx.x * 256 + threadIdx.x;
  int row = tid >> 5;
  int q = tid & 31;
  const float* src;
  unsigned short* dst;
  if (row < nA) {
    int r = mapA ? mapA[row] : row;
    src = embA + (size_t)r * HD;
    dst = outA + (size_t)row * HD;
  } else if (row < nA + nB) {
    int rr = row - nA;
    int r = mapB ? mapB[rr] : rr;
    src = embB + (size_t)r * HD;
    dst = outB + (size_t)rr * HD;
  } else if (row < nA + nB + 4) {
    int which = row - (nA + nB);
    unsigned short* pz =
        (which == 0 ? outA : which == 1 ? outB : which == 2 ? padC : padD) +
        (size_t)padRow * HD;
    ((ushort4*)pz)[q] = make_ushort4(0, 0, 0, 0);
    return;
  } else {
    return;
  }
  float4 v = ((const float4*)src)[q];
  ushort4 o;
  o.x = f2bf(v.x);
  o.y = f2bf(v.y);
  o.z = f2bf(v.z);
  o.w = f2bf(v.w);
  ((ushort4*)dst)[q] = o;
}

// ============ scatter-mean: XCD-local channel slices ============
// Grid = 4 x nodeBlocks; slice = bid & 3 covers 32 channels (64 B = 1 line).
// With round-robin bid->XCD each XCD touches one 3.2 MB table slice -> L2 hits.
// Wave: 1 node; 4 edges per load (16 lanes x 4 B each); padded CSR (x4, zoff).
__global__ __launch_bounds__(256) void k_agg_dual(
    const unsigned short* __restrict__ xA, const int* __restrict__ poffA,
    const int* __restrict__ degA, const int* __restrict__ adjA,
    unsigned short* __restrict__ aggHA, int nA,
    const unsigned short* __restrict__ xB, const int* __restrict__ poffB,
    const int* __restrict__ degB, const int* __restrict__ adjB,
    unsigned short* __restrict__ aggHB, int nB) {
  int bid = blockIdx.x;
  int slice = bid & 3;
  int w = (bid >> 2) * 4 + (int)(threadIdx.x >> 6);
  int lane = threadIdx.x & 63;
  if (w >= nA + nB) return;
  const unsigned short* x;
  const int* adj;
  unsigned short* agg;
  int node, beg, d;
  if (w < nA) {
    x = xA; adj = adjA; agg = aggHA; node = w;
    beg = poffA[w]; d = degA[w];
  } else {
    node = w - nA;
    x = xB; adj = adjB; agg = aggHB;
    beg = poffB[node]; d = degB[node];
  }
  beg = __builtin_amdgcn_readfirstlane(beg);
  d = __builtin_amdgcn_readfirstlane(d);
  int groups = (d + 3) >> 2;
  int j = lane >> 4;                                   // edge within group (0..3)
  unsigned chOff = (unsigned)(slice * 64 + (lane & 15) * 4);

  float s0 = 0.f, s1 = 0.f;
  int it = 0;
  for (; it + 2 <= groups; it += 2) {
    int o0 = __builtin_nontemporal_load(&adj[beg + it * 4 + j]);
    int o1 = __builtin_nontemporal_load(&adj[beg + it * 4 + 4 + j]);
    unsigned v0 = *(const unsigned*)((const char*)x + (unsigned)o0 + chOff);
    unsigned v1 = *(const unsigned*)((const char*)x + (unsigned)o1 + chOff);
    s0 += __uint_as_float(v0 << 16);
    s1 += __uint_as_float(v0 & 0xFFFF0000u);
    s0 += __uint_as_float(v1 << 16);
    s1 += __uint_as_float(v1 & 0xFFFF0000u);
  }
  if (it < groups) {
    int o0 = __builtin_nontemporal_load(&adj[beg + it * 4 + j]);
    unsigned v0 = *(const unsigned*)((const char*)x + (unsigned)o0 + chOff);
    s0 += __uint_as_float(v0 << 16);
    s1 += __uint_as_float(v0 & 0xFFFF0000u);
  }
  // reduce over the 4 edge-groups (lanes differing in bits 4,5)
  s0 += __shfl_xor(s0, 16, 64);
  s0 += __shfl_xor(s0, 32, 64);
  s1 += __shfl_xor(s1, 16, 64);
  s1 += __shfl_xor(s1, 32, 64);
  if (lane < 16) {
    float inv = d ? 1.0f / (float)d : 0.0f;
    unsigned lo16 = f2bf(s0 * inv);
    unsigned hi16 = f2bf(s1 * inv);
    ((unsigned*)(agg + (size_t)node * HD + slice * 32))[lane] = lo16 | (hi16 << 16);
  }
}

// ============ weight prep: all 4 matrices, hi plane only ============
__global__ __launch_bounds__(256) void k_build_pack4(
    const float* __restrict__ wl0, const float* __restrict__ wr0,
    const float* __restrict__ wl1, const float* __restrict__ wr1,
    const float* __restrict__ wl2, const float* __restrict__ wr2,
    const float* __restrict__ wl3, const float* __restrict__ wr3,
    short* __restrict__ Bh0, short* __restrict__ Bh1,
    short* __restrict__ Bh2, short* __restrict__ Bh3) {
  int gidx = blockIdx.x * 256 + threadIdx.x;
  if (gidx >= 4 * 256 * HD) return;
  int m = gidx >> 15;
  int idx = gidx & 32767;
  const float* wl = (m == 0) ? wl0 : (m == 1) ? wl1 : (m == 2) ? wl2 : wl3;
  const float* wr = (m == 0) ? wr0 : (m == 1) ? wr1 : (m == 2) ? wr2 : wr3;
  short* Bh = (m == 0) ? Bh0 : (m == 1) ? Bh1 : (m == 2) ? Bh2 : Bh3;
  int j = idx & 7;
  int lane = (idx >> 3) & 63;
  int cf = (idx >> 9) & 7;
  int ks = idx >> 12;
  int k = ks * 32 + (lane >> 4) * 8 + j;
  int col = cf * 16 + (lane & 15);
  float val = (k < HD) ? wl[col * HD + k] : wr[col * HD + (k - HD)];
  Bh[idx] = (short)f2bf(val);
}

// ============ MFMA GEMM: all-bf16, full-weight LDS, 1 MFMA per frag ============
__device__ __forceinline__ void gemm_body(
    short* __restrict__ lBh,
    const unsigned short* __restrict__ aggH,
    const unsigned short* __restrict__ xB,
    const short* __restrict__ Bh,
    const float* __restrict__ bias,
    const float* __restrict__ resid,
    float* __restrict__ out,
    unsigned short* __restrict__ outB,
    int n, int leaky, int blk) {
  int t = threadIdx.x;  // 0..511
  int lane = t & 63;
  int wv = t >> 6;      // 0..7
  int l15 = lane & 15;
  int kg = lane >> 4;   // 0..3
  int baseRow = blk * 128 + wv * 16;

  // stage full weight plane: 4096 16B units, 8 per thread (layout = global)
#pragma unroll
  for (int i = 0; i < 8; ++i) {
    int u = i * 512 + t;
    ((bf16x8*)lBh)[u] = ((const bf16x8*)Bh)[u];
  }

  f32x4 acc[8];
#pragma unroll
  for (int cf = 0; cf < 8; ++cf) {
    float b = bias[cf * 16 + l15];
    acc[cf] = (f32x4){b, b, b, b};
  }

  int row0 = baseRow + l15;
  int r0c = (row0 < n) ? row0 : (n - 1);
  const unsigned short* a0 = aggH + (size_t)r0c * HD;
  const unsigned short* x0 = xB + (size_t)r0c * HD;

  __syncthreads();
#pragma unroll
  for (int ks = 0; ks < 8; ++ks) {
    const unsigned short* src = (ks < 4) ? (a0 + ks * 32) : (x0 + (ks - 4) * 32);
    bf16x8 ah = *(const bf16x8*)(src + kg * 8);
#pragma unroll
    for (int cf = 0; cf < 8; ++cf) {
      bf16x8 bh = ((const bf16x8*)lBh)[(ks * 8 + cf) * 64 + lane];
      acc[cf] = __builtin_amdgcn_mfma_f32_16x16x32_bf16(ah, bh, acc[cf], 0, 0, 0);
    }
  }

  // epilogue: C layout col = lane&15, row = (lane>>4)*4 + reg
  float ss[4] = {0.f, 0.f, 0.f, 0.f};
#pragma unroll
  for (int cf = 0; cf < 8; ++cf) {
#pragma unroll
    for (int rg = 0; rg < 4; ++rg) ss[rg] += acc[cf][rg] * acc[cf][rg];
  }
#pragma unroll
  for (int rg = 0; rg < 4; ++rg) {
#pragma unroll
    for (int m = 1; m < 16; m <<= 1) ss[rg] += __shfl_xor(ss[rg], m, 64);
  }
#pragma unroll
  for (int rg = 0; rg < 4; ++rg) {
    int row = baseRow + kg * 4 + rg;
    if (row >= n) continue;
    float inv = 1.0f / fmaxf(sqrtf(ss[rg]), 1e-12f);
#pragma unroll
    for (int cf = 0; cf < 8; ++cf) {
      float v = acc[cf][rg] * inv;
      if (leaky) v = (v > 0.f) ? v : 0.01f * v;
      int col = cf * 16 + l15;
      if (resid) v += resid[(size_t)row * HD + col];
      out[(size_t)row * HD + col] = v;
      if (outB) outB[(size_t)row * HD + col] = f2bf(v);
    }
  }
}

// both directions of one layer in a single dispatch (branch is block-uniform)
__global__ __launch_bounds__(512) void k_gemm_dual(
    const unsigned short* aggH0, const unsigned short* xB0, const short* Bh0,
    const float* bias0, const float* res0, float* out0, unsigned short* outB0,
    int n0, int nblk0,
    const unsigned short* aggH1, const unsigned short* xB1, const short* Bh1,
    const float* bias1, const float* res1, float* out1, unsigned short* outB1,
    int n1, int leaky) {
  __shared__ short lBh[32768];  // 64 KB
  int blk = blockIdx.x;
  if (blk < nblk0) {
    gemm_body(lBh, aggH0, xB0, Bh0, bias0, res0, out0, outB0, n0, leaky, blk);
  } else {
    gemm_body(lBh, aggH1, xB1, Bh1, bias1, res1, out1, outB1, n1, leaky,
              blk - nblk0);
  }
}

// ---------------- classifier: 4 edges per wave ----------------
__global__ __launch_bounds__(256) void k_classifier(
    const int* __restrict__ eli, int nL,
    const float* __restrict__ h3s, const float* __restrict__ h3t,
    float* __restrict__ out) {
  int w = (int)((blockIdx.x * 256 + threadIdx.x) >> 6);
  int lane = threadIdx.x & 63;
  int e0 = w * 4;
  if (e0 >= nL) return;
  float2 a[4], b[4];
#pragma unroll
  for (int j = 0; j < 4; ++j) {
    int e = (e0 + j < nL) ? (e0 + j) : (nL - 1);
    int s = eli[e];
    int t = eli[nL + e];
    a[j] = ((const float2*)h3s)[(size_t)s * 64 + lane];
    b[j] = ((const float2*)h3t)[(size_t)t * 64 + lane];
  }
  float p[4];
#pragma unroll
  for (int j = 0; j < 4; ++j) p[j] = a[j].x * b[j].x + a[j].y * b[j].y;
#pragma unroll
  for (int j = 0; j < 4; ++j) {
#pragma unroll
    for (int ofs = 32; ofs > 0; ofs >>= 1) p[j] += __shfl_xor(p[j], ofs, 64);
  }
  if (lane == 0) {
#pragma unroll
    for (int j = 0; j < 4; ++j)
      if (e0 + j < nL) out[e0 + j] = p[j];
  }
}

extern "C" void kernel_launch(void* const* d_in, const int* in_sizes, int n_in,
                              void* d_out, int out_size, void* d_ws, size_t ws_size,
                              hipStream_t stream) {
  (void)n_in;
  (void)out_size;
  const int* snid = (const int*)d_in[0];
  const int* tnid = (const int*)d_in[1];
  const int* ei = (const int*)d_in[2];
  const int* eli = (const int*)d_in[3];
  const float* semb = (const float*)d_in[4];
  const float* temb = (const float*)d_in[5];
  const float* w1l_bt = (const float*)d_in[6];
  const float* w1r_bt = (const float*)d_in[7];
  const float* w1l_tb = (const float*)d_in[8];
  const float* w1r_tb = (const float*)d_in[9];
  const float* w2l_bt = (const float*)d_in[10];
  const float* w2r_bt = (const float*)d_in[11];
  const float* w2l_tb = (const float*)d_in[12];
  const float* w2r_tb = (const float*)d_in[13];
  const float* b1_bt = (const float*)d_in[14];
  const float* b1_tb = (const float*)d_in[15];
  const float* b2_bt = (const float*)d_in[16];
  const float* b2_tb = (const float*)d_in[17];

  const int NS_ = in_sizes[0];
  const int NT_ = in_sizes[1];
  const int nE = in_sizes[2] / 2;
  const int nL = in_sizes[3] / 2;
  float* out = (float*)d_out;

  if (NS_ > 65535 || NT_ > 65535) return;  // packing assumption

  const int nbT = (NT_ + 63) >> 6;
  const int nbS = (NS_ + 63) >> 6;
  if (nbT > 800 || nbS > 800 || nbT + nbS > 1600) return;

  char* ws = (char*)d_ws;
  size_t o = 0;
  auto alloc = [&](size_t bytes) -> void* {
    void* p = ws + o;
    o = (o + bytes + 255) & ~(size_t)255;
    return p;
  };
  int* boffT = (int*)alloc(((size_t)nbT + 1) * 4);
  int* boffS = (int*)alloc(((size_t)nbS + 1) * 4);
  int* bcur = (int*)alloc(((size_t)nbT + nbS) * 4);
  int* bcurT = bcur;
  int* bcurS = bcur + nbT;
  unsigned* ebufT = (unsigned*)alloc((size_t)nE * 4);
  unsigned* ebufS = (unsigned*)alloc((size_t)nE * 4);
  int* poffT = (int*)alloc((size_t)NT_ * 4);
  int* degT = (int*)alloc((size_t)NT_ * 4);
  int* poffS = (int*)alloc((size_t)NS_ * 4);
  int* degS = (int*)alloc((size_t)NS_ * 4);
  int* adjT = (int*)alloc(((size_t)nE + 192 * (size_t)nbT + 64) * 4);
  int* adjS = (int*)alloc(((size_t)nE + 192 * (size_t)nbS + 64) * 4);
  short* Bh1 = (short*)alloc(256 * HD * 2);
  short* Bh2 = (short*)alloc(256 * HD * 2);
  short* Bh3 = (short*)alloc(256 * HD * 2);
  short* Bh4 = (short*)alloc(256 * HD * 2);
  int nmax = imax(NS_, NT_);
  // bf16 node-indexed tables, each with a reserved zero row at index nmax
  unsigned short* bufX0 = (unsigned short*)alloc(((size_t)nmax + 1) * HD * 2);  // semb[snid]
  unsigned short* bufX1 = (unsigned short*)alloc(((size_t)nmax + 1) * HD * 2);  // temb[tnid]
  unsigned short* h1tB = (unsigned short*)alloc(((size_t)nmax + 1) * HD * 2);
  unsigned short* h1sB = (unsigned short*)alloc(((size_t)nmax + 1) * HD * 2);
  // agg output (bf16, single plane)
  unsigned short* aggAH = (unsigned short*)alloc((size_t)nmax * HD * 2);
  unsigned short* aggBH = (unsigned short*)alloc((size_t)nmax * HD * 2);
  float* h1s = (float*)alloc((size_t)NS_ * HD * 4);  // becomes h3s in-place
  float* h1t = (float*)alloc((size_t)NT_ * HD * 4);  // becomes h3t in-place
  if (o > ws_size) return;

  const int zoff = nmax * 256;  // byte offset of the zero row

  // ---- bucket sort -> padded per-node CSR (both directions) ----
  hipMemsetAsync(bcur, 0, ((size_t)nbT + nbS) * 4, stream);
  k_bhist<<<128, 256, 0, stream>>>(ei, nE, bcurT, nbT, bcurS, nbS);
  k_bscan<<<2, 1024, 0, stream>>>(bcurT, boffT, nbT, bcurS, boffS, nbS);
  k_bscatter<<<ceil_div(nE, SC_CH), 256, 0, stream>>>(ei, nE, bcurT, nbT, ebufT,
                                                      bcurS, nbS, ebufS);
  k_bsort2<<<nbT + nbS, 256, 0, stream>>>(ebufT, boffT, poffT, degT, adjT, NT_, nbT,
                                          ebufS, boffS, poffS, degS, adjS, NS_, zoff);

  // ---- bf16 node-indexed feature tables (+ zero pad rows of all 4 tables) ----
  k_cast_gather<<<ceil_div((NS_ + NT_ + 4) * 32, 256), 256, 0, stream>>>(
      semb, snid, bufX0, NS_, temb, tnid, bufX1, NT_, nmax, h1tB, h1sB);

  // ---- weight prep (fragment-ordered bf16 hi, all 4) ----
  k_build_pack4<<<ceil_div(4 * 256 * HD, 256), 256, 0, stream>>>(
      w1l_bt, w1r_bt, w1l_tb, w1r_tb, w2l_bt, w2r_bt, w2l_tb, w2r_tb,
      Bh1, Bh2, Bh3, Bh4);

  int aggGrid = ceil_div(NT_ + NS_, 4) * 4;  // 4 channel-slices per node-block
  int nblkT = ceil_div(NT_, 128);
  int nblkS = ceil_div(NS_, 128);

  // ---- layer 1 ----
  k_agg_dual<<<aggGrid, 256, 0, stream>>>(
      bufX0, poffT, degT, adjT, aggAH, NT_,
      bufX1, poffS, degS, adjS, aggBH, NS_);
  k_gemm_dual<<<nblkT + nblkS, 512, 0, stream>>>(
      aggAH, bufX1, Bh1, b1_bt, nullptr, h1t, h1tB, NT_, nblkT,
      aggBH, bufX0, Bh2, b1_tb, nullptr, h1s, h1sB, NS_, 1);

  // ---- layer 2 (in-place: h1 -> h3) ----
  k_agg_dual<<<aggGrid, 256, 0, stream>>>(
      h1sB, poffT, degT, adjT, aggAH, NT_,
      h1tB, poffS, degS, adjS, aggBH, NS_);
  k_gemm_dual<<<nblkT + nblkS, 512, 0, stream>>>(
      aggAH, h1tB, Bh3, b2_bt, h1t, h1t, nullptr, NT_, nblkT,
      aggBH, h1sB, Bh4, b2_tb, h1s, h1s, nullptr, NS_, 0);

  // ---- classifier ----
  k_classifier<<<ceil_div(nL, 16), 256, 0, stream>>>(eli, nL, h1s, h1t, out);
}

// Round 13
// 240.274 us; speedup vs baseline: 1.7918x; 1.7918x over previous
//
#include <hip/hip_runtime.h>
#include <cstdint>
#include <cstddef>

#define HD 128  // hidden channels

typedef __attribute__((ext_vector_type(8))) short bf16x8;
typedef __attribute__((ext_vector_type(4))) float f32x4;

static inline int ceil_div(int a, int b) { return (a + b - 1) / b; }
static inline int imax(int a, int b) { return a > b ? a : b; }

// f32 -> bf16 (RNE) as raw bits
__device__ __forceinline__ unsigned short f2bf(float f) {
  unsigned u = __float_as_uint(f);
  return (unsigned short)((u + 0x7FFFu + ((u >> 16) & 1u)) >> 16);
}

// ============ bucket sort of edges (64 dst-nodes per bucket) ============
__global__ __launch_bounds__(256) void k_bhist(const int* __restrict__ ei, int nE,
                                               int* __restrict__ histT, int nbT,
                                               int* __restrict__ histS, int nbS) {
  __shared__ int h[1600];
  int nb = nbT + nbS;
  for (int i = threadIdx.x; i < nb; i += 256) h[i] = 0;
  __syncthreads();
  int stride = gridDim.x * 256;
  for (int e = blockIdx.x * 256 + threadIdx.x; e < nE; e += stride) {
    int s = ei[e];
    int t = ei[nE + e];
    atomicAdd(&h[t >> 6], 1);
    atomicAdd(&h[nbT + (s >> 6)], 1);
  }
  __syncthreads();
  for (int i = threadIdx.x; i < nb; i += 256) {
    int v = h[i];
    if (v) {
      if (i < nbT) atomicAdd(&histT[i], v);
      else atomicAdd(&histS[i - nbT], v);
    }
  }
}

__global__ __launch_bounds__(1024) void k_bscan(int* __restrict__ histA, int* __restrict__ offA, int nA,
                                                int* __restrict__ histB, int* __restrict__ offB, int nB) {
  int* hist = blockIdx.x ? histB : histA;
  int* off = blockIdx.x ? offB : offA;
  int n = blockIdx.x ? nB : nA;
  __shared__ int wsum[16];
  int tid = threadIdx.x;
  int lane = tid & 63;
  int wid = tid >> 6;
  int v = (tid < n) ? hist[tid] : 0;
  int x = v;
#pragma unroll
  for (int d = 1; d < 64; d <<= 1) {
    int y = __shfl_up(x, d, 64);
    if (lane >= d) x += y;
  }
  if (lane == 63) wsum[wid] = x;
  __syncthreads();
  if (wid == 0) {
    int s = (lane < 16) ? wsum[lane] : 0;
#pragma unroll
    for (int d = 1; d < 16; d <<= 1) {
      int y = __shfl_up(s, d, 64);
      if (lane >= d) s += y;
    }
    if (lane < 16) wsum[lane] = s;
  }
  __syncthreads();
  int wofs = (wid > 0) ? wsum[wid - 1] : 0;
  int exc = wofs + x - v;
  if (tid < n) {
    off[tid] = exc;
    hist[tid] = exc;  // cursor
  }
  if (tid == 0) off[n] = wsum[15];
}

#define SC_CH 4096  // edges per scatter block (256 thr x 16)
__global__ __launch_bounds__(256) void k_bscatter(const int* __restrict__ ei, int nE,
                                                  int* __restrict__ curT, int nbT,
                                                  unsigned* __restrict__ ebufT,
                                                  int* __restrict__ curS, int nbS,
                                                  unsigned* __restrict__ ebufS) {
  __shared__ unsigned epk[SC_CH];
  __shared__ int cntT[800], baseT[800], cntS[800], baseS[800];
  int tid = threadIdx.x;
  int e0 = blockIdx.x * SC_CH;
  for (int i = tid; i < nbT; i += 256) cntT[i] = 0;
  for (int i = tid; i < nbS; i += 256) cntS[i] = 0;
  for (int i = tid; i < SC_CH; i += 256) {
    int e = e0 + i;
    epk[i] = (e < nE) ? (((unsigned)ei[e] << 16) | (unsigned)ei[nE + e]) : 0xFFFFFFFFu;
  }
  __syncthreads();
  int rT[16], rS[16];
#pragma unroll
  for (int j = 0; j < 16; ++j) {
    int i = tid * 16 + j;
    unsigned p = epk[i];
    if (p != 0xFFFFFFFFu) {
      int t = (int)(p & 0xFFFFu);
      int s = (int)(p >> 16);
      rT[j] = atomicAdd(&cntT[t >> 6], 1);
      rS[j] = atomicAdd(&cntS[s >> 6], 1);
    }
  }
  __syncthreads();
  for (int b = tid; b < nbT; b += 256) baseT[b] = cntT[b] ? atomicAdd(&curT[b], cntT[b]) : 0;
  for (int b = tid; b < nbS; b += 256) baseS[b] = cntS[b] ? atomicAdd(&curS[b], cntS[b]) : 0;
  __syncthreads();
#pragma unroll
  for (int j = 0; j < 16; ++j) {
    int i = tid * 16 + j;
    unsigned p = epk[i];
    if (p != 0xFFFFFFFFu) {
      unsigned t = p & 0xFFFFu;
      unsigned s = p >> 16;
      ebufT[baseT[t >> 6] + rT[j]] = (s << 6) | (t & 63u);
      ebufS[baseS[s >> 6] + rS[j]] = (t << 6) | (s & 63u);
    }
  }
}

// ============ per-bucket counting sort -> padded per-node CSR ============
__global__ __launch_bounds__(256) void k_bsort2(
    const unsigned* __restrict__ ebufT, const int* __restrict__ boffT,
    int* __restrict__ poffT, int* __restrict__ degT, int* __restrict__ adjT,
    int nT, int nbT,
    const unsigned* __restrict__ ebufS, const int* __restrict__ boffS,
    int* __restrict__ poffS, int* __restrict__ degS, int* __restrict__ adjS,
    int nS, int zoff) {
  __shared__ int cnt[64];
  __shared__ int pos[64];
  int b = blockIdx.x;
  const unsigned* ebuf;
  const int* boff;
  int* poff;
  int* deg;
  int* adj;
  int ndst, bb;
  if (b < nbT) {
    ebuf = ebufT; boff = boffT; poff = poffT; deg = degT; adj = adjT;
    ndst = nT; bb = b;
  } else {
    ebuf = ebufS; boff = boffS; poff = poffS; deg = degS; adj = adjS;
    ndst = nS; bb = b - nbT;
  }
  int tid = threadIdx.x;
  if (tid < 64) cnt[tid] = 0;
  __syncthreads();
  int beg = boff[bb], end = boff[bb + 1];
  for (int k = beg + tid; k < end; k += 256) {
    atomicAdd(&cnt[ebuf[k] & 63u], 1);
  }
  __syncthreads();
  if (tid < 64) {
    int v = cnt[tid];
    int pv = v + (v & 1);
    int x = pv;
#pragma unroll
    for (int d = 1; d < 64; d <<= 1) {
      int y = __shfl_up(x, d, 64);
      if (tid >= d) x += y;
    }
    int start = beg + bb * 64 + x - pv;
    pos[tid] = start;
    int node = (bb << 6) + tid;
    if (node < ndst) {
      poff[node] = start;
      deg[node] = v;
    }
  }
  __syncthreads();
  for (int k = beg + tid; k < end; k += 256) {
    unsigned e = ebuf[k];
    int p = atomicAdd(&pos[e & 63u], 1);
    adj[p] = (int)((e >> 6) << 8);  // byte offset = src * 256
  }
  __syncthreads();
  if (tid < 64) {
    if (cnt[tid] & 1) adj[pos[tid]] = zoff;  // pos == start + cnt
  }
}

// ============ gather-cast + pad-row zeroing (4 tables) ============
__global__ __launch_bounds__(256) void k_cast_gather(
    const float* __restrict__ embA, const int* __restrict__ mapA,
    unsigned short* __restrict__ outA, int nA,
    const float* __restrict__ embB, const int* __restrict__ mapB,
    unsigned short* __restrict__ outB, int nB, int padRow,
    unsigned short* __restrict__ padC, unsigned short* __restrict__ padD) {
  int tid = blockIdx.x * 256 + threadIdx.x;
  int row = tid >> 5;
  int q = tid & 31;
  const float* src;
  unsigned short* dst;
  if (row < nA) {
    int r = mapA ? mapA[row] : row;
    src = embA + (size_t)r * HD;
    dst = outA + (size_t)row * HD;
  } else if (row < nA + nB) {
    int rr = row - nA;
    int r = mapB ? mapB[rr] : rr;
    src = embB + (size_t)r * HD;
    dst = outB + (size_t)rr * HD;
  } else if (row < nA + nB + 4) {
    int which = row - (nA + nB);
    unsigned short* pz =
        (which == 0 ? outA : which == 1 ? outB : which == 2 ? padC : padD) +
        (size_t)padRow * HD;
    ((ushort4*)pz)[q] = make_ushort4(0, 0, 0, 0);
    return;
  } else {
    return;
  }
  float4 v = ((const float4*)src)[q];
  ushort4 o;
  o.x = f2bf(v.x);
  o.y = f2bf(v.y);
  o.z = f2bf(v.z);
  o.w = f2bf(v.w);
  ((ushort4*)dst)[q] = o;
}

// ============ scatter-mean: padded CSR, no masks, bf16 output ============
__global__ __launch_bounds__(256) void k_agg_dual(
    const unsigned short* __restrict__ xA, const int* __restrict__ poffA,
    const int* __restrict__ degA, const int* __restrict__ adjA,
    unsigned short* __restrict__ aggHA, int nA,
    const unsigned short* __restrict__ xB, const int* __restrict__ poffB,
    const int* __restrict__ degB, const int* __restrict__ adjB,
    unsigned short* __restrict__ aggHB, int nB) {
  int w = (int)((blockIdx.x * 256 + threadIdx.x) >> 6);
  int lane = threadIdx.x & 63;
  if (w >= nA + nB) return;
  const unsigned short* x;
  const int* adj;
  unsigned short* aggH;
  int node, beg, d;
  if (w < nA) {
    x = xA; adj = adjA; aggH = aggHA; node = w;
    beg = poffA[w]; d = degA[w];
  } else {
    node = w - nA;
    x = xB; adj = adjB; aggH = aggHB;
    beg = poffB[node]; d = degB[node];
  }
  beg = __builtin_amdgcn_readfirstlane(beg);
  d = __builtin_amdgcn_readfirstlane(d);
  int slots = (d + 1) >> 1;
  int h = lane >> 5;
  unsigned loff = (unsigned)((lane & 31) << 3);

  float a0 = 0.f, a1 = 0.f, a2 = 0.f, a3 = 0.f;
  int full = slots >> 2;
  for (int it = 0; it < full; ++it) {
    int base = beg + it * 8;
    uint2 v[4];
#pragma unroll
    for (int s = 0; s < 4; ++s) {
      int oa = __builtin_amdgcn_readfirstlane(adj[base + 2 * s]);
      int ob = __builtin_amdgcn_readfirstlane(adj[base + 2 * s + 1]);
      unsigned off = (unsigned)(h ? ob : oa) + loff;
      v[s] = *(const uint2*)((const char*)x + off);
    }
#pragma unroll
    for (int s = 0; s < 4; ++s) {
      a0 += __uint_as_float(v[s].x << 16);
      a1 += __uint_as_float(v[s].x & 0xFFFF0000u);
      a2 += __uint_as_float(v[s].y << 16);
      a3 += __uint_as_float(v[s].y & 0xFFFF0000u);
    }
  }
  int rem = slots & 3;
  int base = beg + full * 8;
  for (int s = 0; s < rem; ++s) {
    int oa = __builtin_amdgcn_readfirstlane(adj[base + 2 * s]);
    int ob = __builtin_amdgcn_readfirstlane(adj[base + 2 * s + 1]);
    unsigned off = (unsigned)(h ? ob : oa) + loff;
    uint2 v = *(const uint2*)((const char*)x + off);
    a0 += __uint_as_float(v.x << 16);
    a1 += __uint_as_float(v.x & 0xFFFF0000u);
    a2 += __uint_as_float(v.y << 16);
    a3 += __uint_as_float(v.y & 0xFFFF0000u);
  }
  a0 += __shfl_xor(a0, 32, 64);
  a1 += __shfl_xor(a1, 32, 64);
  a2 += __shfl_xor(a2, 32, 64);
  a3 += __shfl_xor(a3, 32, 64);
  if (lane < 32) {
    float inv = d ? 1.0f / (float)d : 0.0f;
    ushort4 o;
    o.x = f2bf(a0 * inv);
    o.y = f2bf(a1 * inv);
    o.z = f2bf(a2 * inv);
    o.w = f2bf(a3 * inv);
    *(ushort4*)(aggH + (size_t)node * HD + lane * 4) = o;
  }
}

// ============ weight prep: all 4 matrices, hi plane only ============
__global__ __launch_bounds__(256) void k_build_pack4(
    const float* __restrict__ wl0, const float* __restrict__ wr0,
    const float* __restrict__ wl1, const float* __restrict__ wr1,
    const float* __restrict__ wl2, const float* __restrict__ wr2,
    const float* __restrict__ wl3, const float* __restrict__ wr3,
    short* __restrict__ Bh0, short* __restrict__ Bh1,
    short* __restrict__ Bh2, short* __restrict__ Bh3) {
  int gidx = blockIdx.x * 256 + threadIdx.x;
  if (gidx >= 4 * 256 * HD) return;
  int m = gidx >> 15;
  int idx = gidx & 32767;
  const float* wl = (m == 0) ? wl0 : (m == 1) ? wl1 : (m == 2) ? wl2 : wl3;
  const float* wr = (m == 0) ? wr0 : (m == 1) ? wr1 : (m == 2) ? wr2 : wr3;
  short* Bh = (m == 0) ? Bh0 : (m == 1) ? Bh1 : (m == 2) ? Bh2 : Bh3;
  int j = idx & 7;
  int lane = (idx >> 3) & 63;
  int cf = (idx >> 9) & 7;
  int ks = idx >> 12;
  int k = ks * 32 + (lane >> 4) * 8 + j;
  int col = cf * 16 + (lane & 15);
  float val = (k < HD) ? wl[col * HD + k] : wr[col * HD + (k - HD)];
  Bh[idx] = (short)f2bf(val);
}

// ============ MFMA GEMM: all-bf16, full-weight LDS, 1 MFMA per frag ============
// Block = 512 threads (8 waves x 16 rows = 128 rows). Full Bh (64 KB) staged
// once. A: aggH (bf16, K 0-127) + xB (bf16 node-indexed table, K 128-255).
// No f32->bf16 conversion in the main loop; no index indirection.
__device__ __forceinline__ void gemm_body(
    short* __restrict__ lBh,
    const unsigned short* __restrict__ aggH,
    const unsigned short* __restrict__ xB,
    const short* __restrict__ Bh,
    const float* __restrict__ bias,
    const float* __restrict__ resid,
    float* __restrict__ out,
    unsigned short* __restrict__ outB,
    int n, int leaky, int blk) {
  int t = threadIdx.x;  // 0..511
  int lane = t & 63;
  int wv = t >> 6;      // 0..7
  int l15 = lane & 15;
  int kg = lane >> 4;   // 0..3
  int baseRow = blk * 128 + wv * 16;

  // stage full weight plane: 4096 16B units, 8 per thread (layout = global)
#pragma unroll
  for (int i = 0; i < 8; ++i) {
    int u = i * 512 + t;
    ((bf16x8*)lBh)[u] = ((const bf16x8*)Bh)[u];
  }

  f32x4 acc[8];
#pragma unroll
  for (int cf = 0; cf < 8; ++cf) {
    float b = bias[cf * 16 + l15];
    acc[cf] = (f32x4){b, b, b, b};
  }

  int row0 = baseRow + l15;
  int r0c = (row0 < n) ? row0 : (n - 1);
  const unsigned short* a0 = aggH + (size_t)r0c * HD;
  const unsigned short* x0 = xB + (size_t)r0c * HD;

  __syncthreads();
#pragma unroll
  for (int ks = 0; ks < 8; ++ks) {
    const unsigned short* src = (ks < 4) ? (a0 + ks * 32) : (x0 + (ks - 4) * 32);
    bf16x8 ah = *(const bf16x8*)(src + kg * 8);
#pragma unroll
    for (int cf = 0; cf < 8; ++cf) {
      bf16x8 bh = ((const bf16x8*)lBh)[(ks * 8 + cf) * 64 + lane];
      acc[cf] = __builtin_amdgcn_mfma_f32_16x16x32_bf16(ah, bh, acc[cf], 0, 0, 0);
    }
  }

  // epilogue: C layout col = lane&15, row = (lane>>4)*4 + reg
  float ss[4] = {0.f, 0.f, 0.f, 0.f};
#pragma unroll
  for (int cf = 0; cf < 8; ++cf) {
#pragma unroll
    for (int rg = 0; rg < 4; ++rg) ss[rg] += acc[cf][rg] * acc[cf][rg];
  }
#pragma unroll
  for (int rg = 0; rg < 4; ++rg) {
#pragma unroll
    for (int m = 1; m < 16; m <<= 1) ss[rg] += __shfl_xor(ss[rg], m, 64);
  }
#pragma unroll
  for (int rg = 0; rg < 4; ++rg) {
    int row = baseRow + kg * 4 + rg;
    if (row >= n) continue;
    float inv = 1.0f / fmaxf(sqrtf(ss[rg]), 1e-12f);
#pragma unroll
    for (int cf = 0; cf < 8; ++cf) {
      float v = acc[cf][rg] * inv;
      if (leaky) v = (v > 0.f) ? v : 0.01f * v;
      int col = cf * 16 + l15;
      if (resid) v += resid[(size_t)row * HD + col];
      out[(size_t)row * HD + col] = v;
      if (outB) outB[(size_t)row * HD + col] = f2bf(v);
    }
  }
}

// both directions of one layer in a single dispatch (branch is block-uniform)
__global__ __launch_bounds__(512) void k_gemm_dual(
    const unsigned short* aggH0, const unsigned short* xB0, const short* Bh0,
    const float* bias0, const float* res0, float* out0, unsigned short* outB0,
    int n0, int nblk0,
    const unsigned short* aggH1, const unsigned short* xB1, const short* Bh1,
    const float* bias1, const float* res1, float* out1, unsigned short* outB1,
    int n1, int leaky) {
  __shared__ short lBh[32768];  // 64 KB
  int blk = blockIdx.x;
  if (blk < nblk0) {
    gemm_body(lBh, aggH0, xB0, Bh0, bias0, res0, out0, outB0, n0, leaky, blk);
  } else {
    gemm_body(lBh, aggH1, xB1, Bh1, bias1, res1, out1, outB1, n1, leaky,
              blk - nblk0);
  }
}

// ---------------- classifier: 4 edges per wave ----------------
__global__ __launch_bounds__(256) void k_classifier(
    const int* __restrict__ eli, int nL,
    const float* __restrict__ h3s, const float* __restrict__ h3t,
    float* __restrict__ out) {
  int w = (int)((blockIdx.x * 256 + threadIdx.x) >> 6);
  int lane = threadIdx.x & 63;
  int e0 = w * 4;
  if (e0 >= nL) return;
  float2 a[4], b[4];
#pragma unroll
  for (int j = 0; j < 4; ++j) {
    int e = (e0 + j < nL) ? (e0 + j) : (nL - 1);
    int s = eli[e];
    int t = eli[nL + e];
    a[j] = ((const float2*)h3s)[(size_t)s * 64 + lane];
    b[j] = ((const float2*)h3t)[(size_t)t * 64 + lane];
  }
  float p[4];
#pragma unroll
  for (int j = 0; j < 4; ++j) p[j] = a[j].x * b[j].x + a[j].y * b[j].y;
#pragma unroll
  for (int j = 0; j < 4; ++j) {
#pragma unroll
    for (int ofs = 32; ofs > 0; ofs >>= 1) p[j] += __shfl_xor(p[j], ofs, 64);
  }
  if (lane == 0) {
#pragma unroll
    for (int j = 0; j < 4; ++j)
      if (e0 + j < nL) out[e0 + j] = p[j];
  }
}

extern "C" void kernel_launch(void* const* d_in, const int* in_sizes, int n_in,
                              void* d_out, int out_size, void* d_ws, size_t ws_size,
                              hipStream_t stream) {
  (void)n_in;
  (void)out_size;
  const int* snid = (const int*)d_in[0];
  const int* tnid = (const int*)d_in[1];
  const int* ei = (const int*)d_in[2];
  const int* eli = (const int*)d_in[3];
  const float* semb = (const float*)d_in[4];
  const float* temb = (const float*)d_in[5];
  const float* w1l_bt = (const float*)d_in[6];
  const float* w1r_bt = (const float*)d_in[7];
  const float* w1l_tb = (const float*)d_in[8];
  const float* w1r_tb = (const float*)d_in[9];
  const float* w2l_bt = (const float*)d_in[10];
  const float* w2r_bt = (const float*)d_in[11];
  const float* w2l_tb = (const float*)d_in[12];
  const float* w2r_tb = (const float*)d_in[13];
  const float* b1_bt = (const float*)d_in[14];
  const float* b1_tb = (const float*)d_in[15];
  const float* b2_bt = (const float*)d_in[16];
  const float* b2_tb = (const float*)d_in[17];

  const int NS_ = in_sizes[0];
  const int NT_ = in_sizes[1];
  const int nE = in_sizes[2] / 2;
  const int nL = in_sizes[3] / 2;
  float* out = (float*)d_out;

  if (NS_ > 65535 || NT_ > 65535) return;  // packing assumption

  const int nbT = (NT_ + 63) >> 6;
  const int nbS = (NS_ + 63) >> 6;
  if (nbT > 800 || nbS > 800 || nbT + nbS > 1600) return;

  char* ws = (char*)d_ws;
  size_t o = 0;
  auto alloc = [&](size_t bytes) -> void* {
    void* p = ws + o;
    o = (o + bytes + 255) & ~(size_t)255;
    return p;
  };
  int* boffT = (int*)alloc(((size_t)nbT + 1) * 4);
  int* boffS = (int*)alloc(((size_t)nbS + 1) * 4);
  int* bcur = (int*)alloc(((size_t)nbT + nbS) * 4);
  int* bcurT = bcur;
  int* bcurS = bcur + nbT;
  unsigned* ebufT = (unsigned*)alloc((size_t)nE * 4);
  unsigned* ebufS = (unsigned*)alloc((size_t)nE * 4);
  int* poffT = (int*)alloc((size_t)NT_ * 4);
  int* degT = (int*)alloc((size_t)NT_ * 4);
  int* poffS = (int*)alloc((size_t)NS_ * 4);
  int* degS = (int*)alloc((size_t)NS_ * 4);
  int* adjT = (int*)alloc(((size_t)nE + 64 * (size_t)nbT + 64) * 4);
  int* adjS = (int*)alloc(((size_t)nE + 64 * (size_t)nbS + 64) * 4);
  short* Bh1 = (short*)alloc(256 * HD * 2);
  short* Bh2 = (short*)alloc(256 * HD * 2);
  short* Bh3 = (short*)alloc(256 * HD * 2);
  short* Bh4 = (short*)alloc(256 * HD * 2);
  int nmax = imax(NS_, NT_);
  // bf16 node-indexed tables, each with a reserved zero row at index nmax
  unsigned short* bufX0 = (unsigned short*)alloc(((size_t)nmax + 1) * HD * 2);  // semb[snid]
  unsigned short* bufX1 = (unsigned short*)alloc(((size_t)nmax + 1) * HD * 2);  // temb[tnid]
  unsigned short* h1tB = (unsigned short*)alloc(((size_t)nmax + 1) * HD * 2);
  unsigned short* h1sB = (unsigned short*)alloc(((size_t)nmax + 1) * HD * 2);
  // agg output (bf16, single plane)
  unsigned short* aggAH = (unsigned short*)alloc((size_t)nmax * HD * 2);
  unsigned short* aggBH = (unsigned short*)alloc((size_t)nmax * HD * 2);
  float* h1s = (float*)alloc((size_t)NS_ * HD * 4);  // becomes h3s in-place
  float* h1t = (float*)alloc((size_t)NT_ * HD * 4);  // becomes h3t in-place
  if (o > ws_size) return;

  const int zoff = nmax * 256;  // byte offset of the zero row

  // ---- bucket sort -> padded per-node CSR (both directions) ----
  hipMemsetAsync(bcur, 0, ((size_t)nbT + nbS) * 4, stream);
  k_bhist<<<128, 256, 0, stream>>>(ei, nE, bcurT, nbT, bcurS, nbS);
  k_bscan<<<2, 1024, 0, stream>>>(bcurT, boffT, nbT, bcurS, boffS, nbS);
  k_bscatter<<<ceil_div(nE, SC_CH), 256, 0, stream>>>(ei, nE, bcurT, nbT, ebufT,
                                                      bcurS, nbS, ebufS);
  k_bsort2<<<nbT + nbS, 256, 0, stream>>>(ebufT, boffT, poffT, degT, adjT, NT_, nbT,
                                          ebufS, boffS, poffS, degS, adjS, NS_, zoff);

  // ---- bf16 node-indexed feature tables (+ zero pad rows of all 4 tables) ----
  k_cast_gather<<<ceil_div((NS_ + NT_ + 4) * 32, 256), 256, 0, stream>>>(
      semb, snid, bufX0, NS_, temb, tnid, bufX1, NT_, nmax, h1tB, h1sB);

  // ---- weight prep (fragment-ordered bf16 hi, all 4) ----
  k_build_pack4<<<ceil_div(4 * 256 * HD, 256), 256, 0, stream>>>(
      w1l_bt, w1r_bt, w1l_tb, w1r_tb, w2l_bt, w2r_bt, w2l_tb, w2r_tb,
      Bh1, Bh2, Bh3, Bh4);

  int aggGrid = ceil_div(NT_ + NS_, 4);  // 1 node per wave, 4 waves per block
  int nblkT = ceil_div(NT_, 128);
  int nblkS = ceil_div(NS_, 128);

  // ---- layer 1 ----
  k_agg_dual<<<aggGrid, 256, 0, stream>>>(
      bufX0, poffT, degT, adjT, aggAH, NT_,
      bufX1, poffS, degS, adjS, aggBH, NS_);
  k_gemm_dual<<<nblkT + nblkS, 512, 0, stream>>>(
      aggAH, bufX1, Bh1, b1_bt, nullptr, h1t, h1tB, NT_, nblkT,
      aggBH, bufX0, Bh2, b1_tb, nullptr, h1s, h1sB, NS_, 1);

  // ---- layer 2 (in-place: h1 -> h3) ----
  k_agg_dual<<<aggGrid, 256, 0, stream>>>(
      h1sB, poffT, degT, adjT, aggAH, NT_,
      h1tB, poffS, degS, adjS, aggBH, NS_);
  k_gemm_dual<<<nblkT + nblkS, 512, 0, stream>>>(
      aggAH, h1tB, Bh3, b2_bt, h1t, h1t, nullptr, NT_, nblkT,
      aggBH, h1sB, Bh4, b2_tb, h1s, h1s, nullptr, NS_, 0);

  // ---- classifier ----
  k_classifier<<<ceil_div(nL, 16), 256, 0, stream>>>(eli, nL, h1s, h1t, out);
}

// Round 14
// 218.916 us; speedup vs baseline: 1.9666x; 1.0976x over previous
//
#include <hip/hip_runtime.h>
#include <cstdint>
#include <cstddef>

#define HD 128  // hidden channels

typedef __attribute__((ext_vector_type(8))) short bf16x8;
typedef __attribute__((ext_vector_type(4))) float f32x4;

static inline int ceil_div(int a, int b) { return (a + b - 1) / b; }
static inline int imax(int a, int b) { return a > b ? a : b; }

// f32 -> bf16 (RNE) as raw bits
__device__ __forceinline__ unsigned short f2bf(float f) {
  unsigned u = __float_as_uint(f);
  return (unsigned short)((u + 0x7FFFu + ((u >> 16) & 1u)) >> 16);
}
__device__ __forceinline__ float bf2f(unsigned short h) {
  return __uint_as_float(((unsigned)h) << 16);
}

// ============ bucket sort of edges (64 dst-nodes per bucket) ============
__global__ __launch_bounds__(256) void k_bhist(const int* __restrict__ ei, int nE,
                                               int* __restrict__ histT, int nbT,
                                               int* __restrict__ histS, int nbS) {
  __shared__ int h[1600];
  int nb = nbT + nbS;
  for (int i = threadIdx.x; i < nb; i += 256) h[i] = 0;
  __syncthreads();
  int stride = gridDim.x * 256;
  for (int e = blockIdx.x * 256 + threadIdx.x; e < nE; e += stride) {
    int s = ei[e];
    int t = ei[nE + e];
    atomicAdd(&h[t >> 6], 1);
    atomicAdd(&h[nbT + (s >> 6)], 1);
  }
  __syncthreads();
  for (int i = threadIdx.x; i < nb; i += 256) {
    int v = h[i];
    if (v) {
      if (i < nbT) atomicAdd(&histT[i], v);
      else atomicAdd(&histS[i - nbT], v);
    }
  }
}

__global__ __launch_bounds__(1024) void k_bscan(int* __restrict__ histA, int* __restrict__ offA, int nA,
                                                int* __restrict__ histB, int* __restrict__ offB, int nB) {
  int* hist = blockIdx.x ? histB : histA;
  int* off = blockIdx.x ? offB : offA;
  int n = blockIdx.x ? nB : nA;
  __shared__ int wsum[16];
  int tid = threadIdx.x;
  int lane = tid & 63;
  int wid = tid >> 6;
  int v = (tid < n) ? hist[tid] : 0;
  int x = v;
#pragma unroll
  for (int d = 1; d < 64; d <<= 1) {
    int y = __shfl_up(x, d, 64);
    if (lane >= d) x += y;
  }
  if (lane == 63) wsum[wid] = x;
  __syncthreads();
  if (wid == 0) {
    int s = (lane < 16) ? wsum[lane] : 0;
#pragma unroll
    for (int d = 1; d < 16; d <<= 1) {
      int y = __shfl_up(s, d, 64);
      if (lane >= d) s += y;
    }
    if (lane < 16) wsum[lane] = s;
  }
  __syncthreads();
  int wofs = (wid > 0) ? wsum[wid - 1] : 0;
  int exc = wofs + x - v;
  if (tid < n) {
    off[tid] = exc;
    hist[tid] = exc;  // cursor
  }
  if (tid == 0) off[n] = wsum[15];
}

#define SC_CH 4096  // edges per scatter block (256 thr x 16)
__global__ __launch_bounds__(256) void k_bscatter(const int* __restrict__ ei, int nE,
                                                  int* __restrict__ curT, int nbT,
                                                  unsigned* __restrict__ ebufT,
                                                  int* __restrict__ curS, int nbS,
                                                  unsigned* __restrict__ ebufS) {
  __shared__ unsigned epk[SC_CH];
  __shared__ int cntT[800], baseT[800], cntS[800], baseS[800];
  int tid = threadIdx.x;
  int e0 = blockIdx.x * SC_CH;
  for (int i = tid; i < nbT; i += 256) cntT[i] = 0;
  for (int i = tid; i < nbS; i += 256) cntS[i] = 0;
  for (int i = tid; i < SC_CH; i += 256) {
    int e = e0 + i;
    epk[i] = (e < nE) ? (((unsigned)ei[e] << 16) | (unsigned)ei[nE + e]) : 0xFFFFFFFFu;
  }
  __syncthreads();
  int rT[16], rS[16];
#pragma unroll
  for (int j = 0; j < 16; ++j) {
    int i = tid * 16 + j;
    unsigned p = epk[i];
    if (p != 0xFFFFFFFFu) {
      int t = (int)(p & 0xFFFFu);
      int s = (int)(p >> 16);
      rT[j] = atomicAdd(&cntT[t >> 6], 1);
      rS[j] = atomicAdd(&cntS[s >> 6], 1);
    }
  }
  __syncthreads();
  for (int b = tid; b < nbT; b += 256) baseT[b] = cntT[b] ? atomicAdd(&curT[b], cntT[b]) : 0;
  for (int b = tid; b < nbS; b += 256) baseS[b] = cntS[b] ? atomicAdd(&curS[b], cntS[b]) : 0;
  __syncthreads();
#pragma unroll
  for (int j = 0; j < 16; ++j) {
    int i = tid * 16 + j;
    unsigned p = epk[i];
    if (p != 0xFFFFFFFFu) {
      unsigned t = p & 0xFFFFu;
      unsigned s = p >> 16;
      ebufT[baseT[t >> 6] + rT[j]] = (s << 6) | (t & 63u);
      ebufS[baseS[s >> 6] + rS[j]] = (t << 6) | (s & 63u);
    }
  }
}

// ============ per-bucket counting sort -> padded per-node CSR ============
__global__ __launch_bounds__(256) void k_bsort2(
    const unsigned* __restrict__ ebufT, const int* __restrict__ boffT,
    int* __restrict__ poffT, int* __restrict__ degT, int* __restrict__ adjT,
    int nT, int nbT,
    const unsigned* __restrict__ ebufS, const int* __restrict__ boffS,
    int* __restrict__ poffS, int* __restrict__ degS, int* __restrict__ adjS,
    int nS, int zoff) {
  __shared__ int cnt[64];
  __shared__ int pos[64];
  int b = blockIdx.x;
  const unsigned* ebuf;
  const int* boff;
  int* poff;
  int* deg;
  int* adj;
  int ndst, bb;
  if (b < nbT) {
    ebuf = ebufT; boff = boffT; poff = poffT; deg = degT; adj = adjT;
    ndst = nT; bb = b;
  } else {
    ebuf = ebufS; boff = boffS; poff = poffS; deg = degS; adj = adjS;
    ndst = nS; bb = b - nbT;
  }
  int tid = threadIdx.x;
  if (tid < 64) cnt[tid] = 0;
  __syncthreads();
  int beg = boff[bb], end = boff[bb + 1];
  for (int k = beg + tid; k < end; k += 256) {
    atomicAdd(&cnt[ebuf[k] & 63u], 1);
  }
  __syncthreads();
  if (tid < 64) {
    int v = cnt[tid];
    int pv = v + (v & 1);
    int x = pv;
#pragma unroll
    for (int d = 1; d < 64; d <<= 1) {
      int y = __shfl_up(x, d, 64);
      if (tid >= d) x += y;
    }
    int start = beg + bb * 64 + x - pv;
    pos[tid] = start;
    int node = (bb << 6) + tid;
    if (node < ndst) {
      poff[node] = start;
      deg[node] = v;
    }
  }
  __syncthreads();
  for (int k = beg + tid; k < end; k += 256) {
    unsigned e = ebuf[k];
    int p = atomicAdd(&pos[e & 63u], 1);
    adj[p] = (int)((e >> 6) << 8);  // byte offset = src * 256
  }
  __syncthreads();
  if (tid < 64) {
    if (cnt[tid] & 1) adj[pos[tid]] = zoff;  // pos == start + cnt
  }
}

// ============ gather-cast + pad-row zeroing (4 tables) ============
__global__ __launch_bounds__(256) void k_cast_gather(
    const float* __restrict__ embA, const int* __restrict__ mapA,
    unsigned short* __restrict__ outA, int nA,
    const float* __restrict__ embB, const int* __restrict__ mapB,
    unsigned short* __restrict__ outB, int nB, int padRow,
    unsigned short* __restrict__ padC, unsigned short* __restrict__ padD) {
  int tid = blockIdx.x * 256 + threadIdx.x;
  int row = tid >> 5;
  int q = tid & 31;
  const float* src;
  unsigned short* dst;
  if (row < nA) {
    int r = mapA ? mapA[row] : row;
    src = embA + (size_t)r * HD;
    dst = outA + (size_t)row * HD;
  } else if (row < nA + nB) {
    int rr = row - nA;
    int r = mapB ? mapB[rr] : rr;
    src = embB + (size_t)r * HD;
    dst = outB + (size_t)rr * HD;
  } else if (row < nA + nB + 4) {
    int which = row - (nA + nB);
    unsigned short* pz =
        (which == 0 ? outA : which == 1 ? outB : which == 2 ? padC : padD) +
        (size_t)padRow * HD;
    ((ushort4*)pz)[q] = make_ushort4(0, 0, 0, 0);
    return;
  } else {
    return;
  }
  float4 v = ((const float4*)src)[q];
  ushort4 o;
  o.x = f2bf(v.x);
  o.y = f2bf(v.y);
  o.z = f2bf(v.z);
  o.w = f2bf(v.w);
  ((ushort4*)dst)[q] = o;
}

// ============ scatter-mean: padded CSR, no masks, bf16 output ============
__global__ __launch_bounds__(256) void k_agg_dual(
    const unsigned short* __restrict__ xA, const int* __restrict__ poffA,
    const int* __restrict__ degA, const int* __restrict__ adjA,
    unsigned short* __restrict__ aggHA, int nA,
    const unsigned short* __restrict__ xB, const int* __restrict__ poffB,
    const int* __restrict__ degB, const int* __restrict__ adjB,
    unsigned short* __restrict__ aggHB, int nB) {
  int w = (int)((blockIdx.x * 256 + threadIdx.x) >> 6);
  int lane = threadIdx.x & 63;
  if (w >= nA + nB) return;
  const unsigned short* x;
  const int* adj;
  unsigned short* aggH;
  int node, beg, d;
  if (w < nA) {
    x = xA; adj = adjA; aggH = aggHA; node = w;
    beg = poffA[w]; d = degA[w];
  } else {
    node = w - nA;
    x = xB; adj = adjB; aggH = aggHB;
    beg = poffB[node]; d = degB[node];
  }
  beg = __builtin_amdgcn_readfirstlane(beg);
  d = __builtin_amdgcn_readfirstlane(d);
  int slots = (d + 1) >> 1;
  int h = lane >> 5;
  unsigned loff = (unsigned)((lane & 31) << 3);

  float a0 = 0.f, a1 = 0.f, a2 = 0.f, a3 = 0.f;
  int full = slots >> 2;
  for (int it = 0; it < full; ++it) {
    int base = beg + it * 8;
    uint2 v[4];
#pragma unroll
    for (int s = 0; s < 4; ++s) {
      int oa = __builtin_amdgcn_readfirstlane(adj[base + 2 * s]);
      int ob = __builtin_amdgcn_readfirstlane(adj[base + 2 * s + 1]);
      unsigned off = (unsigned)(h ? ob : oa) + loff;
      v[s] = *(const uint2*)((const char*)x + off);
    }
#pragma unroll
    for (int s = 0; s < 4; ++s) {
      a0 += __uint_as_float(v[s].x << 16);
      a1 += __uint_as_float(v[s].x & 0xFFFF0000u);
      a2 += __uint_as_float(v[s].y << 16);
      a3 += __uint_as_float(v[s].y & 0xFFFF0000u);
    }
  }
  int rem = slots & 3;
  int base = beg + full * 8;
  for (int s = 0; s < rem; ++s) {
    int oa = __builtin_amdgcn_readfirstlane(adj[base + 2 * s]);
    int ob = __builtin_amdgcn_readfirstlane(adj[base + 2 * s + 1]);
    unsigned off = (unsigned)(h ? ob : oa) + loff;
    uint2 v = *(const uint2*)((const char*)x + off);
    a0 += __uint_as_float(v.x << 16);
    a1 += __uint_as_float(v.x & 0xFFFF0000u);
    a2 += __uint_as_float(v.y << 16);
    a3 += __uint_as_float(v.y & 0xFFFF0000u);
  }
  a0 += __shfl_xor(a0, 32, 64);
  a1 += __shfl_xor(a1, 32, 64);
  a2 += __shfl_xor(a2, 32, 64);
  a3 += __shfl_xor(a3, 32, 64);
  if (lane < 32) {
    float inv = d ? 1.0f / (float)d : 0.0f;
    ushort4 o;
    o.x = f2bf(a0 * inv);
    o.y = f2bf(a1 * inv);
    o.z = f2bf(a2 * inv);
    o.w = f2bf(a3 * inv);
    *(ushort4*)(aggH + (size_t)node * HD + lane * 4) = o;
  }
}

// ============ weight prep: all 4 matrices, hi plane only ============
__global__ __launch_bounds__(256) void k_build_pack4(
    const float* __restrict__ wl0, const float* __restrict__ wr0,
    const float* __restrict__ wl1, const float* __restrict__ wr1,
    const float* __restrict__ wl2, const float* __restrict__ wr2,
    const float* __restrict__ wl3, const float* __restrict__ wr3,
    short* __restrict__ Bh0, short* __restrict__ Bh1,
    short* __restrict__ Bh2, short* __restrict__ Bh3) {
  int gidx = blockIdx.x * 256 + threadIdx.x;
  if (gidx >= 4 * 256 * HD) return;
  int m = gidx >> 15;
  int idx = gidx & 32767;
  const float* wl = (m == 0) ? wl0 : (m == 1) ? wl1 : (m == 2) ? wl2 : wl3;
  const float* wr = (m == 0) ? wr0 : (m == 1) ? wr1 : (m == 2) ? wr2 : wr3;
  short* Bh = (m == 0) ? Bh0 : (m == 1) ? Bh1 : (m == 2) ? Bh2 : Bh3;
  int j = idx & 7;
  int lane = (idx >> 3) & 63;
  int cf = (idx >> 9) & 7;
  int ks = idx >> 12;
  int k = ks * 32 + (lane >> 4) * 8 + j;
  int col = cf * 16 + (lane & 15);
  float val = (k < HD) ? wl[col * HD + k] : wr[col * HD + (k - HD)];
  Bh[idx] = (short)f2bf(val);
}

// ============ MFMA GEMM: all-bf16, full-weight LDS, bf16 in/out ============
// Block = 512 threads (8 waves x 16 rows = 128 rows). Full Bh (64 KB) staged
// once. A: aggH (bf16, K 0-127) + xB (bf16 node-indexed, K 128-255).
// Residual read as bf16; output written as bf16 only. outB == xB (in-place)
// is safe: each wave reads/writes only its own 16-row tile.
__device__ __forceinline__ void gemm_body(
    short* __restrict__ lBh,
    const unsigned short* __restrict__ aggH,
    const unsigned short* __restrict__ xB,
    const short* __restrict__ Bh,
    const float* __restrict__ bias,
    const unsigned short* __restrict__ residB,
    unsigned short* __restrict__ outB,
    int n, int leaky, int blk) {
  int t = threadIdx.x;  // 0..511
  int lane = t & 63;
  int wv = t >> 6;      // 0..7
  int l15 = lane & 15;
  int kg = lane >> 4;   // 0..3
  int baseRow = blk * 128 + wv * 16;

  // stage full weight plane: 4096 16B units, 8 per thread (layout = global)
#pragma unroll
  for (int i = 0; i < 8; ++i) {
    int u = i * 512 + t;
    ((bf16x8*)lBh)[u] = ((const bf16x8*)Bh)[u];
  }

  f32x4 acc[8];
#pragma unroll
  for (int cf = 0; cf < 8; ++cf) {
    float b = bias[cf * 16 + l15];
    acc[cf] = (f32x4){b, b, b, b};
  }

  int row0 = baseRow + l15;
  int r0c = (row0 < n) ? row0 : (n - 1);
  const unsigned short* a0 = aggH + (size_t)r0c * HD;
  const unsigned short* x0 = xB + (size_t)r0c * HD;

  __syncthreads();
#pragma unroll
  for (int ks = 0; ks < 8; ++ks) {
    const unsigned short* src = (ks < 4) ? (a0 + ks * 32) : (x0 + (ks - 4) * 32);
    bf16x8 ah = *(const bf16x8*)(src + kg * 8);
#pragma unroll
    for (int cf = 0; cf < 8; ++cf) {
      bf16x8 bh = ((const bf16x8*)lBh)[(ks * 8 + cf) * 64 + lane];
      acc[cf] = __builtin_amdgcn_mfma_f32_16x16x32_bf16(ah, bh, acc[cf], 0, 0, 0);
    }
  }

  // epilogue: C layout col = lane&15, row = (lane>>4)*4 + reg
  float ss[4] = {0.f, 0.f, 0.f, 0.f};
#pragma unroll
  for (int cf = 0; cf < 8; ++cf) {
#pragma unroll
    for (int rg = 0; rg < 4; ++rg) ss[rg] += acc[cf][rg] * acc[cf][rg];
  }
#pragma unroll
  for (int rg = 0; rg < 4; ++rg) {
#pragma unroll
    for (int m = 1; m < 16; m <<= 1) ss[rg] += __shfl_xor(ss[rg], m, 64);
  }
#pragma unroll
  for (int rg = 0; rg < 4; ++rg) {
    int row = baseRow + kg * 4 + rg;
    if (row >= n) continue;
    float inv = 1.0f / fmaxf(sqrtf(ss[rg]), 1e-12f);
#pragma unroll
    for (int cf = 0; cf < 8; ++cf) {
      float v = acc[cf][rg] * inv;
      if (leaky) v = (v > 0.f) ? v : 0.01f * v;
      int col = cf * 16 + l15;
      if (residB) v += bf2f(residB[(size_t)row * HD + col]);
      outB[(size_t)row * HD + col] = f2bf(v);
    }
  }
}

// both directions of one layer in a single dispatch (branch is block-uniform)
__global__ __launch_bounds__(512) void k_gemm_dual(
    const unsigned short* aggH0, const unsigned short* xB0, const short* Bh0,
    const float* bias0, const unsigned short* res0, unsigned short* outB0,
    int n0, int nblk0,
    const unsigned short* aggH1, const unsigned short* xB1, const short* Bh1,
    const float* bias1, const unsigned short* res1, unsigned short* outB1,
    int n1, int leaky) {
  __shared__ short lBh[32768];  // 64 KB
  int blk = blockIdx.x;
  if (blk < nblk0) {
    gemm_body(lBh, aggH0, xB0, Bh0, bias0, res0, outB0, n0, leaky, blk);
  } else {
    gemm_body(lBh, aggH1, xB1, Bh1, bias1, res1, outB1, n1, leaky,
              blk - nblk0);
  }
}

// ---------------- classifier: bf16 rows, 4 edges per wave ----------------
__global__ __launch_bounds__(256) void k_classifier(
    const int* __restrict__ eli, int nL,
    const unsigned short* __restrict__ h3sB,
    const unsigned short* __restrict__ h3tB,
    float* __restrict__ out) {
  int w = (int)((blockIdx.x * 256 + threadIdx.x) >> 6);
  int lane = threadIdx.x & 63;
  int e0 = w * 4;
  if (e0 >= nL) return;
  unsigned a[4], b[4];
#pragma unroll
  for (int j = 0; j < 4; ++j) {
    int e = (e0 + j < nL) ? (e0 + j) : (nL - 1);
    int s = eli[e];
    int t = eli[nL + e];
    a[j] = ((const unsigned*)h3sB)[(size_t)s * 64 + lane];
    b[j] = ((const unsigned*)h3tB)[(size_t)t * 64 + lane];
  }
  float p[4];
#pragma unroll
  for (int j = 0; j < 4; ++j) {
    float al = __uint_as_float(a[j] << 16);
    float ah = __uint_as_float(a[j] & 0xFFFF0000u);
    float bl = __uint_as_float(b[j] << 16);
    float bh = __uint_as_float(b[j] & 0xFFFF0000u);
    p[j] = al * bl + ah * bh;
  }
#pragma unroll
  for (int j = 0; j < 4; ++j) {
#pragma unroll
    for (int ofs = 32; ofs > 0; ofs >>= 1) p[j] += __shfl_xor(p[j], ofs, 64);
  }
  if (lane == 0) {
#pragma unroll
    for (int j = 0; j < 4; ++j)
      if (e0 + j < nL) out[e0 + j] = p[j];
  }
}

extern "C" void kernel_launch(void* const* d_in, const int* in_sizes, int n_in,
                              void* d_out, int out_size, void* d_ws, size_t ws_size,
                              hipStream_t stream) {
  (void)n_in;
  (void)out_size;
  const int* snid = (const int*)d_in[0];
  const int* tnid = (const int*)d_in[1];
  const int* ei = (const int*)d_in[2];
  const int* eli = (const int*)d_in[3];
  const float* semb = (const float*)d_in[4];
  const float* temb = (const float*)d_in[5];
  const float* w1l_bt = (const float*)d_in[6];
  const float* w1r_bt = (const float*)d_in[7];
  const float* w1l_tb = (const float*)d_in[8];
  const float* w1r_tb = (const float*)d_in[9];
  const float* w2l_bt = (const float*)d_in[10];
  const float* w2r_bt = (const float*)d_in[11];
  const float* w2l_tb = (const float*)d_in[12];
  const float* w2r_tb = (const float*)d_in[13];
  const float* b1_bt = (const float*)d_in[14];
  const float* b1_tb = (const float*)d_in[15];
  const float* b2_bt = (const float*)d_in[16];
  const float* b2_tb = (const float*)d_in[17];

  const int NS_ = in_sizes[0];
  const int NT_ = in_sizes[1];
  const int nE = in_sizes[2] / 2;
  const int nL = in_sizes[3] / 2;
  float* out = (float*)d_out;

  if (NS_ > 65535 || NT_ > 65535) return;  // packing assumption

  const int nbT = (NT_ + 63) >> 6;
  const int nbS = (NS_ + 63) >> 6;
  if (nbT > 800 || nbS > 800 || nbT + nbS > 1600) return;

  char* ws = (char*)d_ws;
  size_t o = 0;
  auto alloc = [&](size_t bytes) -> void* {
    void* p = ws + o;
    o = (o + bytes + 255) & ~(size_t)255;
    return p;
  };
  int* boffT = (int*)alloc(((size_t)nbT + 1) * 4);
  int* boffS = (int*)alloc(((size_t)nbS + 1) * 4);
  int* bcur = (int*)alloc(((size_t)nbT + nbS) * 4);
  int* bcurT = bcur;
  int* bcurS = bcur + nbT;
  unsigned* ebufT = (unsigned*)alloc((size_t)nE * 4);
  unsigned* ebufS = (unsigned*)alloc((size_t)nE * 4);
  int* poffT = (int*)alloc((size_t)NT_ * 4);
  int* degT = (int*)alloc((size_t)NT_ * 4);
  int* poffS = (int*)alloc((size_t)NS_ * 4);
  int* degS = (int*)alloc((size_t)NS_ * 4);
  int* adjT = (int*)alloc(((size_t)nE + 64 * (size_t)nbT + 64) * 4);
  int* adjS = (int*)alloc(((size_t)nE + 64 * (size_t)nbS + 64) * 4);
  short* Bh1 = (short*)alloc(256 * HD * 2);
  short* Bh2 = (short*)alloc(256 * HD * 2);
  short* Bh3 = (short*)alloc(256 * HD * 2);
  short* Bh4 = (short*)alloc(256 * HD * 2);
  int nmax = imax(NS_, NT_);
  // bf16 node-indexed tables, each with a reserved zero row at index nmax
  unsigned short* bufX0 = (unsigned short*)alloc(((size_t)nmax + 1) * HD * 2);  // semb[snid]
  unsigned short* bufX1 = (unsigned short*)alloc(((size_t)nmax + 1) * HD * 2);  // temb[tnid]
  unsigned short* h1tB = (unsigned short*)alloc(((size_t)nmax + 1) * HD * 2);   // h1t -> h3t (in-place)
  unsigned short* h1sB = (unsigned short*)alloc(((size_t)nmax + 1) * HD * 2);   // h1s -> h3s (in-place)
  // agg output (bf16, single plane)
  unsigned short* aggAH = (unsigned short*)alloc((size_t)nmax * HD * 2);
  unsigned short* aggBH = (unsigned short*)alloc((size_t)nmax * HD * 2);
  if (o > ws_size) return;

  const int zoff = nmax * 256;  // byte offset of the zero row

  // ---- bucket sort -> padded per-node CSR (both directions) ----
  hipMemsetAsync(bcur, 0, ((size_t)nbT + nbS) * 4, stream);
  k_bhist<<<128, 256, 0, stream>>>(ei, nE, bcurT, nbT, bcurS, nbS);
  k_bscan<<<2, 1024, 0, stream>>>(bcurT, boffT, nbT, bcurS, boffS, nbS);
  k_bscatter<<<ceil_div(nE, SC_CH), 256, 0, stream>>>(ei, nE, bcurT, nbT, ebufT,
                                                      bcurS, nbS, ebufS);
  k_bsort2<<<nbT + nbS, 256, 0, stream>>>(ebufT, boffT, poffT, degT, adjT, NT_, nbT,
                                          ebufS, boffS, poffS, degS, adjS, NS_, zoff);

  // ---- bf16 node-indexed feature tables (+ zero pad rows of all 4 tables) ----
  k_cast_gather<<<ceil_div((NS_ + NT_ + 4) * 32, 256), 256, 0, stream>>>(
      semb, snid, bufX0, NS_, temb, tnid, bufX1, NT_, nmax, h1tB, h1sB);

  // ---- weight prep (fragment-ordered bf16 hi, all 4) ----
  k_build_pack4<<<ceil_div(4 * 256 * HD, 256), 256, 0, stream>>>(
      w1l_bt, w1r_bt, w1l_tb, w1r_tb, w2l_bt, w2r_bt, w2l_tb, w2r_tb,
      Bh1, Bh2, Bh3, Bh4);

  int aggGrid = ceil_div(NT_ + NS_, 4);  // 1 node per wave, 4 waves per block
  int nblkT = ceil_div(NT_, 128);
  int nblkS = ceil_div(NS_, 128);

  // ---- layer 1 (outputs bf16 h1 tables only) ----
  k_agg_dual<<<aggGrid, 256, 0, stream>>>(
      bufX0, poffT, degT, adjT, aggAH, NT_,
      bufX1, poffS, degS, adjS, aggBH, NS_);
  k_gemm_dual<<<nblkT + nblkS, 512, 0, stream>>>(
      aggAH, bufX1, Bh1, b1_bt, nullptr, h1tB, NT_, nblkT,
      aggBH, bufX0, Bh2, b1_tb, nullptr, h1sB, NS_, 1);

  // ---- layer 2 (residual from bf16 h1; h3 written in-place over h1B) ----
  k_agg_dual<<<aggGrid, 256, 0, stream>>>(
      h1sB, poffT, degT, adjT, aggAH, NT_,
      h1tB, poffS, degS, adjS, aggBH, NS_);
  k_gemm_dual<<<nblkT + nblkS, 512, 0, stream>>>(
      aggAH, h1tB, Bh3, b2_bt, h1tB, h1tB, NT_, nblkT,
      aggBH, h1sB, Bh4, b2_tb, h1sB, h1sB, NS_, 0);

  // ---- classifier (bf16 h3 tables) ----
  k_classifier<<<ceil_div(nL, 16), 256, 0, stream>>>(eli, nL, h1sB, h1tB, out);
}